// Round 6
// baseline (463.912 us; speedup 1.0000x reference)
//
#include <hip/hip_runtime.h>

#define N_NODES 100000
#define N_EDGES 1600000
#define NREP 8

typedef _Float16 half8 __attribute__((ext_vector_type(8)));
typedef float floatx4 __attribute__((ext_vector_type(4)));

// ---------------- CSR build ----------------
// pass1: one packed u64 atomic per edge into an XCD-local replica:
// [count:24 | weight-sum fixed20:40]. Replica = blockIdx&7 (round-robin XCD).
// Returned count field = ticket within (node, replica).

__global__ __launch_bounds__(256) void edge_pass1(const int* __restrict__ ei,
                                                  const float* __restrict__ ew,
                                                  unsigned long long* __restrict__ packed,
                                                  unsigned short* __restrict__ tickets) {
    int e = blockIdx.x * 256 + threadIdx.x;
    if (e >= N_EDGES) return;
    int r = blockIdx.x & (NREP - 1);
    int col = ei[N_EDGES + e];
    unsigned fx = (unsigned)(ew[e] * 1048576.0f + 0.5f);
    unsigned long long old =
        atomicAdd(&packed[(size_t)r * N_NODES + col], (1ULL << 40) | (unsigned long long)fx);
    tickets[e] = (unsigned short)((unsigned)((old >> 40) & 0x1FFF) | ((unsigned)r << 13));
}

__global__ __launch_bounds__(256) void node_pass(const unsigned long long* __restrict__ packed,
                                                 float* __restrict__ dis,
                                                 int* __restrict__ offs,
                                                 int* __restrict__ gcur,
                                                 unsigned* __restrict__ offsR) {
    int j = blockIdx.x * 256 + threadIdx.x;
    int lane = threadIdx.x & 63;
    int c = 0;
    int cr[NREP];
    if (j < N_NODES) {
        unsigned long long sum = 0;
        #pragma unroll
        for (int r = 0; r < NREP; r++) {
            unsigned long long v = packed[(size_t)r * N_NODES + j];
            cr[r] = (int)(v >> 40);
            sum += v;
        }
        c = (int)(sum >> 40);
        float deg = (float)(sum & ((1ULL << 40) - 1)) * (1.0f / 1048576.0f);
        dis[j] = rsqrtf(deg + 1.0f);
    }
    // wave-level inclusive scan of counts -> one atomic per wave
    int s = c;
    #pragma unroll
    for (int off = 1; off < 64; off <<= 1) {
        int t = __shfl_up(s, off, 64);
        if (lane >= off) s += t;
    }
    int total = __shfl(s, 63, 64);
    int base = 0;
    if (lane == 0) base = atomicAdd(gcur, total);
    base = __shfl(base, 0, 64);
    if (j < N_NODES) {
        int o = base + (s - c);
        offs[j] = o;
        unsigned run = (unsigned)o;
        #pragma unroll
        for (int r = 0; r < NREP; r++) {
            offsR[(size_t)r * N_NODES + j] = run;
            run += (unsigned)cr[r];
        }
    }
}

// csr entry: [f16 weight bits sans sign :15 | src :17]
__global__ __launch_bounds__(256) void edge_pass2(const int* __restrict__ ei,
                                                  const float* __restrict__ ew,
                                                  const float* __restrict__ dis,
                                                  const unsigned* __restrict__ offsR,
                                                  const unsigned short* __restrict__ tickets,
                                                  unsigned* __restrict__ csr) {
    int e = blockIdx.x * 256 + threadIdx.x;
    if (e >= N_EDGES) return;
    int row = ei[e];
    int col = ei[N_EDGES + e];
    unsigned tk = tickets[e];
    int r = tk >> 13;
    int slot = (int)offsR[(size_t)r * N_NODES + col] + (int)(tk & 0x1FFF);
    float nw = dis[row] * ew[e] * dis[col];
    _Float16 h = (_Float16)nw;
    unsigned short hb;
    __builtin_memcpy(&hb, &h, 2);
    csr[slot] = ((unsigned)hb << 17) | (unsigned)row;
}

// ---------------- weight prep: Wt[col][k] = (f16)W[k][col], 4 matrices ----------------

__global__ __launch_bounds__(256) void prep_w(const float* __restrict__ W0,
                                              const float* __restrict__ W1,
                                              const float* __restrict__ W2,
                                              const float* __restrict__ W3,
                                              _Float16* __restrict__ Wt) {
    int m = blockIdx.x >> 4;
    const float* W = (m == 0) ? W0 : (m == 1) ? W1 : (m == 2) ? W2 : W3;
    _Float16* o = Wt + m * 16384;
    int base = (blockIdx.x & 15) * 1024 + threadIdx.x * 4;
    int col = base >> 7;
    int k0 = base & 127;
    #pragma unroll
    for (int i = 0; i < 4; i++) o[base + i] = (_Float16)W[(k0 + i) * 128 + col];
}

// ---------------- encoder layer 1: [N,16]@[16,128]+b, relu -> f16 ----------------

__global__ __launch_bounds__(256) void enc1_kernel(const float* __restrict__ x,
                                                   const float* __restrict__ W1,
                                                   const float* __restrict__ b1,
                                                   _Float16* __restrict__ out) {
    __shared__ float sX[256 * 17];
    __shared__ float sW[2048];
    __shared__ float sb[128];
    int t = threadIdx.x;
    int base = blockIdx.x * 256;
    for (int i = t; i < 512; i += 256) ((float4*)sW)[i] = ((const float4*)W1)[i];
    if (t < 128) sb[t] = b1[t];
    #pragma unroll
    for (int i = 0; i < 4; i++) {
        int f = i * 1024 + t * 4;
        int row = f >> 4, k = f & 15;
        float4 v = make_float4(0.f, 0.f, 0.f, 0.f);
        if (base + row < N_NODES) v = *(const float4*)(x + (size_t)(base + row) * 16 + k);
        *(float4*)(sX + row * 17 + k) = v;
    }
    __syncthreads();
    int row = base + t;
    if (row >= N_NODES) return;
    float xr[16];
    #pragma unroll
    for (int k = 0; k < 16; k++) xr[k] = sX[t * 17 + k];
    #pragma unroll 4
    for (int cb = 0; cb < 16; cb++) {
        float acc[8];
        #pragma unroll
        for (int jj = 0; jj < 8; jj++) acc[jj] = sb[cb * 8 + jj];
        #pragma unroll
        for (int k = 0; k < 16; k++) {
            float xv = xr[k];
            #pragma unroll
            for (int jj = 0; jj < 8; jj++) acc[jj] = fmaf(xv, sW[k * 128 + cb * 8 + jj], acc[jj]);
        }
        half8 h;
        #pragma unroll
        for (int jj = 0; jj < 8; jj++) h[jj] = (_Float16)fmaxf(acc[jj], 0.f);
        *(half8*)(out + (size_t)row * 128 + cb * 8) = h;
    }
}

// ---------------- f16 MFMA GEMM: [N,128] @ [128,128], grid-stride tiles ----------------

#define GEMM_GRID 522

template <bool BIAS, bool RELU, bool DEC>
__global__ __launch_bounds__(256, 2) void gemm_mfma(const _Float16* __restrict__ A,
                                                    const _Float16* __restrict__ Wt,
                                                    const float* __restrict__ bias,
                                                    _Float16* __restrict__ C,
                                                    const float* __restrict__ W2,
                                                    const float* __restrict__ b2,
                                                    float* __restrict__ sm_out) {
    __shared__ _Float16 sA[64 * 128];
    __shared__ _Float16 sE[DEC ? 64 : 64 * 128];
    __shared__ float sW2[DEC ? 256 : 1];
    int t = threadIdx.x;
    int lane = t & 63;
    int w = t >> 6;
    int l15 = lane & 15;
    int l4 = lane >> 4;

    half8 bfrag[8][4];
    #pragma unroll
    for (int n = 0; n < 8; n++)
        #pragma unroll
        for (int kk = 0; kk < 4; kk++)
            bfrag[n][kk] = *(const half8*)(Wt + (n * 16 + l15) * 128 + kk * 32 + l4 * 8);

    float bcol[8];
    if constexpr (BIAS) {
        #pragma unroll
        for (int n = 0; n < 8; n++) bcol[n] = bias[n * 16 + l15];
    }
    float b20 = 0.f, b21 = 0.f;
    if constexpr (DEC) {
        if (t < 256) sW2[t] = W2[t];
        b20 = b2[0]; b21 = b2[1];
    }

    const int NT = (N_NODES + 63) / 64;
    for (int tile = blockIdx.x; tile < NT; tile += GEMM_GRID) {
        const _Float16* Ag = A + (size_t)tile * 64 * 128;
        #pragma unroll
        for (int i = 0; i < 4; i++) {
            int c = i * 256 + t;
            int row = c >> 4;
            int g = (c & 15) ^ (row & 7);
            const _Float16* src = Ag + row * 128 + g * 8;
            __builtin_amdgcn_global_load_lds(
                (const __attribute__((address_space(1))) void*)src,
                (__attribute__((address_space(3))) void*)(sA + (size_t)(i * 256 + w * 64) * 8),
                16, 0, 0);
        }
        __syncthreads();

        floatx4 acc[8];
        #pragma unroll
        for (int n = 0; n < 8; n++) acc[n] = (floatx4)(0.f);

        #pragma unroll
        for (int kk = 0; kk < 4; kk++) {
            int rloc = w * 16 + l15;
            int cl = kk * 4 + l4;
            int s = cl ^ (rloc & 7);
            half8 af = *(const half8*)(sA + rloc * 128 + s * 8);
            #pragma unroll
            for (int n = 0; n < 8; n++)
                acc[n] = __builtin_amdgcn_mfma_f32_16x16x32_f16(af, bfrag[n][kk], acc[n], 0, 0, 0);
        }

        size_t base_row = (size_t)tile * 64;
        if constexpr (DEC) {
            #pragma unroll
            for (int r = 0; r < 4; r++) {
                float p0 = 0.f, p1 = 0.f;
                #pragma unroll
                for (int n = 0; n < 8; n++) {
                    float v = acc[n][r];
                    if constexpr (BIAS) v += bcol[n];
                    if constexpr (RELU) v = fmaxf(v, 0.f);
                    int ch = n * 16 + l15;
                    p0 = fmaf(v, sW2[ch * 2 + 0], p0);
                    p1 = fmaf(v, sW2[ch * 2 + 1], p1);
                }
                #pragma unroll
                for (int m = 1; m < 16; m <<= 1) {
                    p0 += __shfl_xor(p0, m, 64);
                    p1 += __shfl_xor(p1, m, 64);
                }
                size_t grow = base_row + w * 16 + l4 * 4 + r;
                if (l15 == 0 && grow < N_NODES) {
                    float z0 = p0 + b20, z1 = p1 + b21;
                    float mx = fmaxf(z0, z1);
                    float e0 = expf(z0 - mx), e1 = expf(z1 - mx);
                    float si = 1.f / (e0 + e1);
                    *(float2*)(sm_out + grow * 2) = make_float2(e0 * si, e1 * si);
                }
            }
            __syncthreads();
        } else {
            #pragma unroll
            for (int n = 0; n < 8; n++) {
                #pragma unroll
                for (int r = 0; r < 4; r++) {
                    float v = acc[n][r];
                    if constexpr (BIAS) v += bcol[n];
                    if constexpr (RELU) v = fmaxf(v, 0.f);
                    int row = w * 16 + l4 * 4 + r;
                    sE[row * 128 + n * 16 + l15] = (_Float16)v;
                }
            }
            __syncthreads();
            #pragma unroll
            for (int i = 0; i < 4; i++) {
                int c = i * 256 + t;
                int row = c >> 4;
                if (base_row + row < N_NODES) {
                    *(float4*)((char*)C + (base_row + row) * 256 + (c & 15) * 16) =
                        *(const float4*)((const char*)sE + (size_t)c * 16);
                }
            }
        }
    }
}

// ---------------- GCN aggregation v2 ----------------
// Wave = 4 groups x 16 lanes. Group g owns edge e+g; lane q owns 8-channel
// chunk (half8, 16B gather). 8 edges in flight; cross-group shfl_xor reduce.

__device__ __forceinline__ float wdec(unsigned u) {
    unsigned short b = (unsigned short)(u >> 17);
    _Float16 h;
    __builtin_memcpy(&h, &b, 2);
    return (float)h;
}

__global__ __launch_bounds__(256) void agg_kernel(const _Float16* __restrict__ m,
                                                  const int* __restrict__ offs,
                                                  const unsigned long long* __restrict__ packed,
                                                  const unsigned* __restrict__ csr,
                                                  const float* __restrict__ dis,
                                                  const float* __restrict__ bias,
                                                  _Float16* __restrict__ out) {
    int wave = threadIdx.x >> 6;
    int lane = threadIdx.x & 63;
    int g = lane >> 4;      // edge slot within wave
    int q = lane & 15;      // 8-channel chunk
    int j = blockIdx.x * 4 + wave;
    if (j >= N_NODES) return;
    int s = offs[j];
    int num = 0;
    {
        // total in-degree = sum of replica counts
        #pragma unroll
        for (int r = 0; r < NREP; r++) num += (int)(packed[(size_t)r * N_NODES + j] >> 40);
    }

    float acc[8];
    if (g == 0) {
        float d = dis[j];
        float dd = d * d;
        half8 mv = *(const half8*)(m + (size_t)j * 128 + q * 8);
        #pragma unroll
        for (int i = 0; i < 8; i++) acc[i] = dd * (float)mv[i];
    } else {
        #pragma unroll
        for (int i = 0; i < 8; i++) acc[i] = 0.f;
    }

    int e = 0;
    for (; e + 8 <= num; e += 8) {
        unsigned u0 = csr[s + e + g];
        unsigned u1 = csr[s + e + 4 + g];
        half8 r0 = *(const half8*)(m + (size_t)(u0 & 0x1FFFF) * 128 + q * 8);
        half8 r1 = *(const half8*)(m + (size_t)(u1 & 0x1FFFF) * 128 + q * 8);
        float w0 = wdec(u0);
        float w1 = wdec(u1);
        #pragma unroll
        for (int i = 0; i < 8; i++) acc[i] = fmaf(w0, (float)r0[i], acc[i]);
        #pragma unroll
        for (int i = 0; i < 8; i++) acc[i] = fmaf(w1, (float)r1[i], acc[i]);
    }
    for (; e < num; e += 4) {
        if (e + g < num) {
            unsigned u0 = csr[s + e + g];
            half8 r0 = *(const half8*)(m + (size_t)(u0 & 0x1FFFF) * 128 + q * 8);
            float w0 = wdec(u0);
            #pragma unroll
            for (int i = 0; i < 8; i++) acc[i] = fmaf(w0, (float)r0[i], acc[i]);
        }
    }

    #pragma unroll
    for (int i = 0; i < 8; i++) {
        acc[i] += __shfl_xor(acc[i], 16, 64);
        acc[i] += __shfl_xor(acc[i], 32, 64);
    }

    if (g == 0) {
        float4 b0 = *(const float4*)(bias + q * 8);
        float4 b1 = *(const float4*)(bias + q * 8 + 4);
        float bb[8] = {b0.x, b0.y, b0.z, b0.w, b1.x, b1.y, b1.z, b1.w};
        half8 o;
        #pragma unroll
        for (int i = 0; i < 8; i++) o[i] = (_Float16)fmaxf(acc[i] + bb[i], 0.f);
        *(half8*)(out + (size_t)j * 128 + q * 8) = o;
    }
}

// ---------------- launch ----------------

extern "C" void kernel_launch(void* const* d_in, const int* in_sizes, int n_in,
                              void* d_out, int out_size, void* d_ws, size_t ws_size,
                              hipStream_t stream) {
    const float* x      = (const float*)d_in[0];
    const int*   ei     = (const int*)d_in[1];
    const float* ew     = (const float*)d_in[2];
    const float* enc_W1 = (const float*)d_in[3];
    const float* enc_b1 = (const float*)d_in[4];
    const float* enc_W2 = (const float*)d_in[5];
    const float* enc_b2 = (const float*)d_in[6];
    const float* c1_W   = (const float*)d_in[7];
    const float* c1_b   = (const float*)d_in[8];
    const float* c2_W   = (const float*)d_in[9];
    const float* c2_b   = (const float*)d_in[10];
    const float* dec_W1 = (const float*)d_in[11];
    const float* dec_b1 = (const float*)d_in[12];
    const float* dec_W2 = (const float*)d_in[13];
    const float* dec_b2 = (const float*)d_in[14];
    float* out = (float*)d_out;

    char* ws = (char*)d_ws;
    _Float16* B1 = (_Float16*)(ws);                          // 25,600,000
    _Float16* B2 = (_Float16*)(ws + 25600000);               // 25,600,000
    _Float16* Wt = (_Float16*)(ws + 51200000);               // 131,072
    unsigned long long* packed = (unsigned long long*)(ws + 51331072);  // 6,400,000 (8 replicas)
    int*   gcur    = (int*)  (ws + 57731072);                // 256
    float* dis     = (float*)(ws + 57731328);                // 400,000
    int*   offs    = (int*)  (ws + 58131328);                // 400,000
    unsigned* offsR = (unsigned*)(ws + 58531328);            // 3,200,000
    unsigned short* tickets = (unsigned short*)(ws + 61731328); // 3,200,000
    unsigned* csr  = (unsigned*)(ws + 64931328);             // 6,400,000
    // end ~71.3 MB

    // zero packed replicas + gcur (contiguous)
    hipMemsetAsync(packed, 0, 6400256, stream);

    edge_pass1<<<(N_EDGES + 255) / 256, 256, 0, stream>>>(ei, ew, packed, tickets);
    node_pass<<<(N_NODES + 255) / 256, 256, 0, stream>>>(packed, dis, offs, gcur, offsR);
    edge_pass2<<<(N_EDGES + 255) / 256, 256, 0, stream>>>(ei, ew, dis, offsR, tickets, csr);

    prep_w<<<64, 256, 0, stream>>>(enc_W2, c1_W, c2_W, dec_W1, Wt);
    enc1_kernel<<<(N_NODES + 255) / 256, 256, 0, stream>>>(x, enc_W1, enc_b1, B1);

    gemm_mfma<true, false, false><<<GEMM_GRID, 256, 0, stream>>>(B1, Wt + 0 * 16384, enc_b2, B2, nullptr, nullptr, nullptr);
    gemm_mfma<false, false, false><<<GEMM_GRID, 256, 0, stream>>>(B2, Wt + 1 * 16384, nullptr, B1, nullptr, nullptr, nullptr);
    agg_kernel<<<N_NODES / 4, 256, 0, stream>>>(B1, offs, packed, csr, dis, c1_b, B2);
    gemm_mfma<false, false, false><<<GEMM_GRID, 256, 0, stream>>>(B2, Wt + 2 * 16384, nullptr, B1, nullptr, nullptr, nullptr);
    agg_kernel<<<N_NODES / 4, 256, 0, stream>>>(B1, offs, packed, csr, dis, c2_b, B2);
    gemm_mfma<true, true, true><<<GEMM_GRID, 256, 0, stream>>>(B2, Wt + 3 * 16384, dec_b1, nullptr, dec_W2, dec_b2, out);
}

// Round 7
// 447.569 us; speedup vs baseline: 1.0365x; 1.0365x over previous
//
#include <hip/hip_runtime.h>

#define N_NODES 100000
#define N_EDGES 1600000
#define NREP 8

typedef _Float16 half8 __attribute__((ext_vector_type(8)));
typedef float floatx4 __attribute__((ext_vector_type(4)));

__device__ __forceinline__ int xcc_id() {
    unsigned v;
    asm volatile("s_getreg_b32 %0, hwreg(HW_REG_XCC_ID)" : "=s"(v));
    return (int)(v & (NREP - 1));
}

// ---------------- CSR build ----------------
// pass1: one packed u64 atomic per edge into the TRUE-XCD-local replica,
// executed at WORKGROUP scope -> RMW resolves in the local L2 (never leaves
// the XCD). [count:24 | weight-sum fixed20:40]. Ticket = (replica, local idx).

__global__ __launch_bounds__(256) void edge_pass1(const int* __restrict__ ei,
                                                  const float* __restrict__ ew,
                                                  unsigned long long* __restrict__ packed,
                                                  unsigned short* __restrict__ tickets) {
    int e = blockIdx.x * 256 + threadIdx.x;
    if (e >= N_EDGES) return;
    int r = xcc_id();
    int col = ei[N_EDGES + e];
    unsigned fx = (unsigned)(ew[e] * 1048576.0f + 0.5f);
    unsigned long long old = __hip_atomic_fetch_add(
        &packed[(size_t)r * N_NODES + col],
        (1ULL << 40) | (unsigned long long)fx,
        __ATOMIC_RELAXED, __HIP_MEMORY_SCOPE_WORKGROUP);
    tickets[e] = (unsigned short)((unsigned)((old >> 40) & 0x1FFF) | ((unsigned)r << 13));
}

__global__ __launch_bounds__(256) void node_pass(const unsigned long long* __restrict__ packed,
                                                 float* __restrict__ dis,
                                                 int* __restrict__ offs,
                                                 int* __restrict__ gcur,
                                                 unsigned* __restrict__ offsR,
                                                 int* __restrict__ cnt) {
    int j = blockIdx.x * 256 + threadIdx.x;
    int lane = threadIdx.x & 63;
    int c = 0;
    int cr[NREP];
    if (j < N_NODES) {
        unsigned long long sum = 0;
        #pragma unroll
        for (int r = 0; r < NREP; r++) {
            unsigned long long v = packed[(size_t)r * N_NODES + j];
            cr[r] = (int)(v >> 40);
            sum += v;
        }
        c = (int)(sum >> 40);
        float deg = (float)(sum & ((1ULL << 40) - 1)) * (1.0f / 1048576.0f);
        dis[j] = rsqrtf(deg + 1.0f);
        cnt[j] = c;
    }
    // wave-level inclusive scan of counts -> one atomic per wave
    int s = c;
    #pragma unroll
    for (int off = 1; off < 64; off <<= 1) {
        int t = __shfl_up(s, off, 64);
        if (lane >= off) s += t;
    }
    int total = __shfl(s, 63, 64);
    int base = 0;
    if (lane == 0) base = atomicAdd(gcur, total);
    base = __shfl(base, 0, 64);
    if (j < N_NODES) {
        int o = base + (s - c);
        offs[j] = o;
        unsigned run = (unsigned)o;
        #pragma unroll
        for (int r = 0; r < NREP; r++) {
            offsR[(size_t)r * N_NODES + j] = run;
            run += (unsigned)cr[r];
        }
    }
}

// csr entry: [f16 weight bits sans sign :15 | src :17]
__global__ __launch_bounds__(256) void edge_pass2(const int* __restrict__ ei,
                                                  const float* __restrict__ ew,
                                                  const float* __restrict__ dis,
                                                  const unsigned* __restrict__ offsR,
                                                  const unsigned short* __restrict__ tickets,
                                                  unsigned* __restrict__ csr) {
    int e = blockIdx.x * 256 + threadIdx.x;
    if (e >= N_EDGES) return;
    int row = ei[e];
    int col = ei[N_EDGES + e];
    unsigned tk = tickets[e];
    int r = tk >> 13;
    int slot = (int)offsR[(size_t)r * N_NODES + col] + (int)(tk & 0x1FFF);
    float nw = dis[row] * ew[e] * dis[col];
    _Float16 h = (_Float16)nw;
    unsigned short hb;
    __builtin_memcpy(&hb, &h, 2);
    csr[slot] = ((unsigned)hb << 17) | (unsigned)row;
}

// ---------------- weight prep: Wt[col][k] = (f16)W[k][col], 4 matrices ----------------

__global__ __launch_bounds__(256) void prep_w(const float* __restrict__ W0,
                                              const float* __restrict__ W1,
                                              const float* __restrict__ W2,
                                              const float* __restrict__ W3,
                                              _Float16* __restrict__ Wt) {
    int m = blockIdx.x >> 4;
    const float* W = (m == 0) ? W0 : (m == 1) ? W1 : (m == 2) ? W2 : W3;
    _Float16* o = Wt + m * 16384;
    int base = (blockIdx.x & 15) * 1024 + threadIdx.x * 4;
    int col = base >> 7;
    int k0 = base & 127;
    #pragma unroll
    for (int i = 0; i < 4; i++) o[base + i] = (_Float16)W[(k0 + i) * 128 + col];
}

// ---------------- encoder layer 1: [N,16]@[16,128]+b, relu -> f16 ----------------

__global__ __launch_bounds__(256) void enc1_kernel(const float* __restrict__ x,
                                                   const float* __restrict__ W1,
                                                   const float* __restrict__ b1,
                                                   _Float16* __restrict__ out) {
    __shared__ float sX[256 * 17];
    __shared__ float sW[2048];
    __shared__ float sb[128];
    int t = threadIdx.x;
    int base = blockIdx.x * 256;
    for (int i = t; i < 512; i += 256) ((float4*)sW)[i] = ((const float4*)W1)[i];
    if (t < 128) sb[t] = b1[t];
    #pragma unroll
    for (int i = 0; i < 4; i++) {
        int f = i * 1024 + t * 4;
        int row = f >> 4, k = f & 15;
        float4 v = make_float4(0.f, 0.f, 0.f, 0.f);
        if (base + row < N_NODES) v = *(const float4*)(x + (size_t)(base + row) * 16 + k);
        *(float4*)(sX + row * 17 + k) = v;
    }
    __syncthreads();
    int row = base + t;
    if (row >= N_NODES) return;
    float xr[16];
    #pragma unroll
    for (int k = 0; k < 16; k++) xr[k] = sX[t * 17 + k];
    #pragma unroll 4
    for (int cb = 0; cb < 16; cb++) {
        float acc[8];
        #pragma unroll
        for (int jj = 0; jj < 8; jj++) acc[jj] = sb[cb * 8 + jj];
        #pragma unroll
        for (int k = 0; k < 16; k++) {
            float xv = xr[k];
            #pragma unroll
            for (int jj = 0; jj < 8; jj++) acc[jj] = fmaf(xv, sW[k * 128 + cb * 8 + jj], acc[jj]);
        }
        half8 h;
        #pragma unroll
        for (int jj = 0; jj < 8; jj++) h[jj] = (_Float16)fmaxf(acc[jj], 0.f);
        *(half8*)(out + (size_t)row * 128 + cb * 8) = h;
    }
}

// ---------------- f16 MFMA GEMM: [N,128] @ [128,128], grid-stride tiles ----------------

#define GEMM_GRID 522

template <bool BIAS, bool RELU, bool DEC>
__global__ __launch_bounds__(256, 2) void gemm_mfma(const _Float16* __restrict__ A,
                                                    const _Float16* __restrict__ Wt,
                                                    const float* __restrict__ bias,
                                                    _Float16* __restrict__ C,
                                                    const float* __restrict__ W2,
                                                    const float* __restrict__ b2,
                                                    float* __restrict__ sm_out) {
    __shared__ _Float16 sA[64 * 128];
    __shared__ _Float16 sE[DEC ? 64 : 64 * 128];
    __shared__ float sW2[DEC ? 256 : 1];
    int t = threadIdx.x;
    int lane = t & 63;
    int w = t >> 6;
    int l15 = lane & 15;
    int l4 = lane >> 4;

    half8 bfrag[8][4];
    #pragma unroll
    for (int n = 0; n < 8; n++)
        #pragma unroll
        for (int kk = 0; kk < 4; kk++)
            bfrag[n][kk] = *(const half8*)(Wt + (n * 16 + l15) * 128 + kk * 32 + l4 * 8);

    float bcol[8];
    if constexpr (BIAS) {
        #pragma unroll
        for (int n = 0; n < 8; n++) bcol[n] = bias[n * 16 + l15];
    }
    float b20 = 0.f, b21 = 0.f;
    if constexpr (DEC) {
        if (t < 256) sW2[t] = W2[t];
        b20 = b2[0]; b21 = b2[1];
    }

    const int NT = (N_NODES + 63) / 64;
    for (int tile = blockIdx.x; tile < NT; tile += GEMM_GRID) {
        const _Float16* Ag = A + (size_t)tile * 64 * 128;
        #pragma unroll
        for (int i = 0; i < 4; i++) {
            int c = i * 256 + t;
            int row = c >> 4;
            int g = (c & 15) ^ (row & 7);
            const _Float16* src = Ag + row * 128 + g * 8;
            __builtin_amdgcn_global_load_lds(
                (const __attribute__((address_space(1))) void*)src,
                (__attribute__((address_space(3))) void*)(sA + (size_t)(i * 256 + w * 64) * 8),
                16, 0, 0);
        }
        __syncthreads();

        floatx4 acc[8];
        #pragma unroll
        for (int n = 0; n < 8; n++) acc[n] = (floatx4)(0.f);

        #pragma unroll
        for (int kk = 0; kk < 4; kk++) {
            int rloc = w * 16 + l15;
            int cl = kk * 4 + l4;
            int s = cl ^ (rloc & 7);
            half8 af = *(const half8*)(sA + rloc * 128 + s * 8);
            #pragma unroll
            for (int n = 0; n < 8; n++)
                acc[n] = __builtin_amdgcn_mfma_f32_16x16x32_f16(af, bfrag[n][kk], acc[n], 0, 0, 0);
        }

        size_t base_row = (size_t)tile * 64;
        if constexpr (DEC) {
            #pragma unroll
            for (int r = 0; r < 4; r++) {
                float p0 = 0.f, p1 = 0.f;
                #pragma unroll
                for (int n = 0; n < 8; n++) {
                    float v = acc[n][r];
                    if constexpr (BIAS) v += bcol[n];
                    if constexpr (RELU) v = fmaxf(v, 0.f);
                    int ch = n * 16 + l15;
                    p0 = fmaf(v, sW2[ch * 2 + 0], p0);
                    p1 = fmaf(v, sW2[ch * 2 + 1], p1);
                }
                #pragma unroll
                for (int m = 1; m < 16; m <<= 1) {
                    p0 += __shfl_xor(p0, m, 64);
                    p1 += __shfl_xor(p1, m, 64);
                }
                size_t grow = base_row + w * 16 + l4 * 4 + r;
                if (l15 == 0 && grow < N_NODES) {
                    float z0 = p0 + b20, z1 = p1 + b21;
                    float mx = fmaxf(z0, z1);
                    float e0 = expf(z0 - mx), e1 = expf(z1 - mx);
                    float si = 1.f / (e0 + e1);
                    *(float2*)(sm_out + grow * 2) = make_float2(e0 * si, e1 * si);
                }
            }
            __syncthreads();
        } else {
            #pragma unroll
            for (int n = 0; n < 8; n++) {
                #pragma unroll
                for (int r = 0; r < 4; r++) {
                    float v = acc[n][r];
                    if constexpr (BIAS) v += bcol[n];
                    if constexpr (RELU) v = fmaxf(v, 0.f);
                    int row = w * 16 + l4 * 4 + r;
                    sE[row * 128 + n * 16 + l15] = (_Float16)v;
                }
            }
            __syncthreads();
            #pragma unroll
            for (int i = 0; i < 4; i++) {
                int c = i * 256 + t;
                int row = c >> 4;
                if (base_row + row < N_NODES) {
                    *(float4*)((char*)C + (base_row + row) * 256 + (c & 15) * 16) =
                        *(const float4*)((const char*)sE + (size_t)c * 16);
                }
            }
        }
    }
}

// ---------------- GCN aggregation v2 ----------------
// Wave = 4 groups x 16 lanes. Group g owns edge e+g; lane q owns 8-channel
// chunk (half8, 16B gather). 8 edges in flight; cross-group shfl_xor reduce.

__device__ __forceinline__ float wdec(unsigned u) {
    unsigned short b = (unsigned short)(u >> 17);
    _Float16 h;
    __builtin_memcpy(&h, &b, 2);
    return (float)h;
}

__global__ __launch_bounds__(256) void agg_kernel(const _Float16* __restrict__ m,
                                                  const int* __restrict__ offs,
                                                  const int* __restrict__ cnt,
                                                  const unsigned* __restrict__ csr,
                                                  const float* __restrict__ dis,
                                                  const float* __restrict__ bias,
                                                  _Float16* __restrict__ out) {
    int wave = threadIdx.x >> 6;
    int lane = threadIdx.x & 63;
    int g = lane >> 4;      // edge slot within wave
    int q = lane & 15;      // 8-channel chunk
    int j = blockIdx.x * 4 + wave;
    if (j >= N_NODES) return;
    int s = offs[j];
    int num = cnt[j];

    float acc[8];
    if (g == 0) {
        float d = dis[j];
        float dd = d * d;
        half8 mv = *(const half8*)(m + (size_t)j * 128 + q * 8);
        #pragma unroll
        for (int i = 0; i < 8; i++) acc[i] = dd * (float)mv[i];
    } else {
        #pragma unroll
        for (int i = 0; i < 8; i++) acc[i] = 0.f;
    }

    int e = 0;
    for (; e + 8 <= num; e += 8) {
        unsigned u0 = csr[s + e + g];
        unsigned u1 = csr[s + e + 4 + g];
        half8 r0 = *(const half8*)(m + (size_t)(u0 & 0x1FFFF) * 128 + q * 8);
        half8 r1 = *(const half8*)(m + (size_t)(u1 & 0x1FFFF) * 128 + q * 8);
        float w0 = wdec(u0);
        float w1 = wdec(u1);
        #pragma unroll
        for (int i = 0; i < 8; i++) acc[i] = fmaf(w0, (float)r0[i], acc[i]);
        #pragma unroll
        for (int i = 0; i < 8; i++) acc[i] = fmaf(w1, (float)r1[i], acc[i]);
    }
    for (; e < num; e += 4) {
        if (e + g < num) {
            unsigned u0 = csr[s + e + g];
            half8 r0 = *(const half8*)(m + (size_t)(u0 & 0x1FFFF) * 128 + q * 8);
            float w0 = wdec(u0);
            #pragma unroll
            for (int i = 0; i < 8; i++) acc[i] = fmaf(w0, (float)r0[i], acc[i]);
        }
    }

    #pragma unroll
    for (int i = 0; i < 8; i++) {
        acc[i] += __shfl_xor(acc[i], 16, 64);
        acc[i] += __shfl_xor(acc[i], 32, 64);
    }

    if (g == 0) {
        float4 b0 = *(const float4*)(bias + q * 8);
        float4 b1 = *(const float4*)(bias + q * 8 + 4);
        float bb[8] = {b0.x, b0.y, b0.z, b0.w, b1.x, b1.y, b1.z, b1.w};
        half8 o;
        #pragma unroll
        for (int i = 0; i < 8; i++) o[i] = (_Float16)fmaxf(acc[i] + bb[i], 0.f);
        *(half8*)(out + (size_t)j * 128 + q * 8) = o;
    }
}

// ---------------- launch ----------------

extern "C" void kernel_launch(void* const* d_in, const int* in_sizes, int n_in,
                              void* d_out, int out_size, void* d_ws, size_t ws_size,
                              hipStream_t stream) {
    const float* x      = (const float*)d_in[0];
    const int*   ei     = (const int*)d_in[1];
    const float* ew     = (const float*)d_in[2];
    const float* enc_W1 = (const float*)d_in[3];
    const float* enc_b1 = (const float*)d_in[4];
    const float* enc_W2 = (const float*)d_in[5];
    const float* enc_b2 = (const float*)d_in[6];
    const float* c1_W   = (const float*)d_in[7];
    const float* c1_b   = (const float*)d_in[8];
    const float* c2_W   = (const float*)d_in[9];
    const float* c2_b   = (const float*)d_in[10];
    const float* dec_W1 = (const float*)d_in[11];
    const float* dec_b1 = (const float*)d_in[12];
    const float* dec_W2 = (const float*)d_in[13];
    const float* dec_b2 = (const float*)d_in[14];
    float* out = (float*)d_out;

    char* ws = (char*)d_ws;
    _Float16* B1 = (_Float16*)(ws);                          // 25,600,000
    _Float16* B2 = (_Float16*)(ws + 25600000);               // 25,600,000
    _Float16* Wt = (_Float16*)(ws + 51200000);               // 131,072
    unsigned long long* packed = (unsigned long long*)(ws + 51331072);  // 6,400,000 (8 replicas)
    int*   gcur    = (int*)  (ws + 57731072);                // 256
    float* dis     = (float*)(ws + 57731328);                // 400,000
    int*   offs    = (int*)  (ws + 58131328);                // 400,000
    int*   cnt     = (int*)  (ws + 58531328);                // 400,000
    unsigned* offsR = (unsigned*)(ws + 58931328);            // 3,200,000
    unsigned short* tickets = (unsigned short*)(ws + 62131328); // 3,200,000
    unsigned* csr  = (unsigned*)(ws + 65331328);             // 6,400,000
    // end ~71.7 MB

    // zero packed replicas + gcur (contiguous)
    hipMemsetAsync(packed, 0, 6400256, stream);

    edge_pass1<<<(N_EDGES + 255) / 256, 256, 0, stream>>>(ei, ew, packed, tickets);
    node_pass<<<(N_NODES + 255) / 256, 256, 0, stream>>>(packed, dis, offs, gcur, offsR, cnt);
    edge_pass2<<<(N_EDGES + 255) / 256, 256, 0, stream>>>(ei, ew, dis, offsR, tickets, csr);

    prep_w<<<64, 256, 0, stream>>>(enc_W2, c1_W, c2_W, dec_W1, Wt);
    enc1_kernel<<<(N_NODES + 255) / 256, 256, 0, stream>>>(x, enc_W1, enc_b1, B1);

    gemm_mfma<true, false, false><<<GEMM_GRID, 256, 0, stream>>>(B1, Wt + 0 * 16384, enc_b2, B2, nullptr, nullptr, nullptr);
    gemm_mfma<false, false, false><<<GEMM_GRID, 256, 0, stream>>>(B2, Wt + 1 * 16384, nullptr, B1, nullptr, nullptr, nullptr);
    agg_kernel<<<N_NODES / 4, 256, 0, stream>>>(B1, offs, cnt, csr, dis, c1_b, B2);
    gemm_mfma<false, false, false><<<GEMM_GRID, 256, 0, stream>>>(B2, Wt + 2 * 16384, nullptr, B1, nullptr, nullptr, nullptr);
    agg_kernel<<<N_NODES / 4, 256, 0, stream>>>(B1, offs, cnt, csr, dis, c2_b, B2);
    gemm_mfma<true, true, true><<<GEMM_GRID, 256, 0, stream>>>(B2, Wt + 3 * 16384, dec_b1, nullptr, dec_W2, dec_b2, out);
}